// Round 14
// baseline (10163.795 us; speedup 1.0000x reference)
//
#include <hip/hip_runtime.h>

// DualEncoderLSTMDense — Round 14: INSTRUMENTATION via shadow-kernel ablation.
// Real kernel <0> = bit-identical R13 (passes, 3.19ms). Shadows (scratch outputs,
// gated on ws_size) isolate phase costs via their dispatch dur_us in rocprof:
//   <1> noBar  : no poll wait (publishes kept)      -> sync-coupling cost
//   <2> noH    : no h-part A loads (MFMAs kept)     -> coherent h-read cost
//   <4> plainH : h via plain cached loads (shadow)  -> coherence-path cost
// d_out path touches only <0>'s planes -> output identical (absmax 1.953125e-3).

typedef unsigned short u16;
typedef unsigned long long u64;
typedef __attribute__((ext_vector_type(8))) short    s16x8;
typedef __attribute__((ext_vector_type(4))) float    f32x4;
typedef __attribute__((ext_vector_type(4))) unsigned u32x4;

#define MFMA(a, b, c) __builtin_amdgcn_mfma_f32_16x16x32_bf16((a), (b), (c), 0, 0, 0)

__device__ __forceinline__ u16 f2bf(float f) {
    union { float f; unsigned u; } v; v.f = f;
    unsigned r = v.u + 0x7FFFu + ((v.u >> 16) & 1u);
    return (u16)(r >> 16);
}
__device__ __forceinline__ float bf2f(u16 h) {
    union { unsigned u; float f; } v; v.u = ((unsigned)h) << 16;
    return v.f;
}
__device__ __forceinline__ float sigm(float x) { return 1.0f / (1.0f + expf(-x)); }

__global__ __launch_bounds__(256) void transpose_split(const float* __restrict__ src,
        u16* __restrict__ dhi, u16* __restrict__ dlo, int R, int C)
{
    __shared__ float tile[32][33];
    const int bx = blockIdx.x * 32;
    const int by = blockIdx.y * 32;
    for (int i = threadIdx.y; i < 32; i += 8)
        tile[i][threadIdx.x] = src[(size_t)(by + i) * C + bx + threadIdx.x];
    __syncthreads();
    for (int i = threadIdx.y; i < 32; i += 8) {
        float v = tile[threadIdx.x][i];
        u16 hi = f2bf(v);
        size_t o = (size_t)(bx + i) * R + by + threadIdx.x;
        dhi[o] = hi;
        dlo[o] = f2bf(v - bf2f(hi));
    }
}

__global__ __launch_bounds__(256) void zero_state(unsigned* __restrict__ h0p,
        unsigned* __restrict__ ctr)
{
    const int i = blockIdx.x * 256 + threadIdx.x;   // grid 1024*256 = 262144
    h0p[i] = 0;
    if (i < 32) ctr[i * 32] = 0;                    // zero all 4 counter sets
}

// MODE: 0 real | 1 noBar | 2 noH | 4 plainH
template<int MODE>
__global__ __launch_bounds__(256, 1) void lstm_persist(
        const float* __restrict__ emb, const int* __restrict__ qtok, const int* __restrict__ rtok,
        const int* __restrict__ qlen, const int* __restrict__ rlen,
        const u16* __restrict__ Wt_hi, const u16* __restrict__ Wt_lo,
        const float* __restrict__ bias, const float* __restrict__ wi,
        const float* __restrict__ wf, const float* __restrict__ wo,
        unsigned* __restrict__ h0p, unsigned* __restrict__ h1p,
        unsigned* __restrict__ ctr)
{
    __shared__ u16 whi_h[32768];   // 64 KiB: W_hi rows [4g*16c] x K 256..767, XOR-swizzled

    const int tid = threadIdx.x, lane = tid & 63, w = tid >> 6;
    const int bid = blockIdx.x;
    const int rowTile = bid & 7, hidTile = bid >> 3;
    const int row0 = rowTile * 64 + w * 16, hid0 = hidTile * 16;
    const int frow = lane & 15, kgrp = lane >> 4;
    const int sw = (frow & 7) << 4;

    for (int i = tid; i < 4096; i += 256) {
        const int gc = i >> 6, c16 = i & 63;
        const int g = gc >> 4, cc = gc & 15;
        const s16x8 v = *(const s16x8*)(Wt_hi + (size_t)(g * 512 + hid0 + cc) * 768 + 256 + c16 * 8);
        *(s16x8*)((char*)whi_h + ((gc * 1024 + c16 * 16) ^ ((gc & 7) << 4))) = v;
    }

    const int   ohid = hid0 + frow;
    const float bi  = bias[ohid];
    const float bj  = bias[512 + ohid];
    const float bff = bias[1024 + ohid];
    const float bo  = bias[1536 + ohid];
    const float wiv = wi[ohid], wfv = wf[ohid], wov = wo[ohid];
    const int   arow = row0 + frow;
    const int*  tokp = (arow < 256) ? (qtok + arow * 128) : (rtok + (arow - 256) * 128);
    const u16*  whi_base[4];
    const u16*  wlo_base[4];
    #pragma unroll
    for (int g = 0; g < 4; ++g) {
        whi_base[g] = Wt_hi + (size_t)(g * 512 + hid0 + frow) * 768;
        wlo_base[g] = Wt_lo + (size_t)(g * 512 + hid0 + frow) * 768;
    }
    int lenv[4];
    #pragma unroll
    for (int r = 0; r < 4; ++r) {
        const int rr = row0 + kgrp * 4 + r;
        lenv[r] = (rr < 256) ? qlen[rr] : rlen[rr - 256];
    }
    float c_reg[4] = {0, 0, 0, 0}, h_reg[4] = {0, 0, 0, 0};

    __syncthreads();

    unsigned* myctr = ctr + rowTile * 32;

    for (int t = 0; t < 128; ++t) {
        const unsigned* rd = (t & 1) ? h1p : h0p;
        unsigned*       wr = (t & 1) ? h0p : h1p;

        // ---- x-part (overlaps barrier stragglers) ----
        const int    tok  = tokp[t];
        const float* xrow = emb + (size_t)tok * 256 + kgrp * 8;
        f32x4 fv[16];
        #pragma unroll
        for (int i = 0; i < 16; ++i)
            fv[i] = *(const f32x4*)(xrow + (i >> 1) * 32 + (i & 1) * 4);

        f32x4 acc[4] = {{0,0,0,0},{0,0,0,0},{0,0,0,0},{0,0,0,0}};
        s16x8 xsave;

        #pragma unroll
        for (int ks = 0; ks < 8; ++ks) {
            const f32x4 v0 = fv[2 * ks], v1 = fv[2 * ks + 1];
            const float vv[8] = {v0[0], v0[1], v0[2], v0[3], v1[0], v1[1], v1[2], v1[3]};
            s16x8 xh, xl;
            #pragma unroll
            for (int e = 0; e < 8; ++e) {
                const u16 hb = f2bf(vv[e]);
                xh[e] = (short)hb;
                xl[e] = (short)f2bf(vv[e] - bf2f(hb));
            }
            if (ks == 7) xsave = xh;
            const int kk = ks * 32 + kgrp * 8;
            #pragma unroll
            for (int g = 0; g < 4; ++g) {
                const s16x8 bh = *(const s16x8*)(whi_base[g] + kk);
                const s16x8 bl = *(const s16x8*)(wlo_base[g] + kk);
                acc[g] = MFMA(xh, bh, acc[g]);
                acc[g] = MFMA(xl, bh, acc[g]);
                acc[g] = MFMA(xh, bl, acc[g]);
            }
        }

        // ---- barrier wait (modes 0,2,4): wave-autonomous, relaxed-load poll ----
        if constexpr (MODE != 1) {
            if (lane == 0) {
                const unsigned target = 128u * (unsigned)t;
                while (__hip_atomic_load(myctr, __ATOMIC_RELAXED, __HIP_MEMORY_SCOPE_AGENT) < target)
                    __builtin_amdgcn_s_sleep(2);
            }
        }
        asm volatile("" ::: "memory");

        const unsigned* hrd = rd + arow * 512 + kgrp * 8;

        // ---- h-part, K 256..767 ----
        #pragma unroll 2
        for (int ks = 0; ks < 16; ++ks) {
            const int kh = ks * 32;
            s16x8 ah, al;
            if constexpr (MODE == 2) {
                ah = xsave; al = xsave;                 // no h loads; MFMAs kept live
            } else if constexpr (MODE == 4) {
                const u32x4 a0 = *(const u32x4*)(hrd + kh);       // plain cached loads
                const u32x4 a1 = *(const u32x4*)(hrd + kh + 4);
                #pragma unroll
                for (int i = 0; i < 4; ++i) {
                    ah[i]     = (short)(u16)a0[i];
                    al[i]     = (short)(u16)(a0[i] >> 16);
                    ah[4 + i] = (short)(u16)a1[i];
                    al[4 + i] = (short)(u16)(a1[i] >> 16);
                }
            } else {
                #pragma unroll
                for (int i = 0; i < 4; ++i) {
                    const u64 v = __hip_atomic_load((const u64*)(hrd + kh + 2 * i),
                                                    __ATOMIC_RELAXED, __HIP_MEMORY_SCOPE_AGENT);
                    const unsigned w0 = (unsigned)v, w1 = (unsigned)(v >> 32);
                    ah[2 * i]     = (short)(u16)w0;
                    al[2 * i]     = (short)(u16)(w0 >> 16);
                    ah[2 * i + 1] = (short)(u16)w1;
                    al[2 * i + 1] = (short)(u16)(w1 >> 16);
                }
            }
            #pragma unroll
            for (int g = 0; g < 4; ++g) {
                const int gr = g * 16 + frow;
                const s16x8 bh = *(const s16x8*)((const char*)whi_h + ((gr * 1024 + (kh + kgrp * 8) * 2) ^ sw));
                const s16x8 bl = *(const s16x8*)(wlo_base[g] + 256 + kh + kgrp * 8);
                acc[g] = MFMA(ah, bh, acc[g]);
                acc[g] = MFMA(al, bh, acc[g]);
                acc[g] = MFMA(ah, bl, acc[g]);
                acc[g] = MFMA(al, bl, acc[g]);
            }
        }

        // ---- gates + peepholes + masking; publish h packed via sc1 store ----
        #pragma unroll
        for (int r = 0; r < 4; ++r) {
            const float cold = c_reg[r];
            const float ig = sigm(acc[0][r] + bi + wiv * cold);
            const float jg = tanhf(acc[1][r] + bj);
            const float fg = sigm(acc[2][r] + bff + wfv * cold + 2.0f);
            const float cn = fg * cold + ig * jg;
            const float og = sigm(acc[3][r] + bo + wov * cn);
            const float hn = og * tanhf(cn);
            const bool upd = (t < lenv[r]);
            c_reg[r] = upd ? cn : c_reg[r];
            h_reg[r] = upd ? hn : h_reg[r];
            const int off = (row0 + kgrp * 4 + r) * 512 + ohid;
            const u16 hb = f2bf(h_reg[r]);
            const u16 lb = f2bf(h_reg[r] - bf2f(hb));
            __hip_atomic_store(wr + off, ((unsigned)lb << 16) | (unsigned)hb,
                               __ATOMIC_RELAXED, __HIP_MEMORY_SCOPE_AGENT);
        }

        // ---- per-wave publish ----
        asm volatile("s_waitcnt vmcnt(0)" ::: "memory");
        if (lane == 0)
            __hip_atomic_fetch_add(myctr, 1u, __ATOMIC_RELAXED, __HIP_MEMORY_SCOPE_AGENT);
        asm volatile("" ::: "memory");
    }
}

__global__ __launch_bounds__(256) void qt_kernel(
        const unsigned* __restrict__ hpk,
        const u16* __restrict__ Mt_hi, const u16* __restrict__ Mt_lo, float* __restrict__ qt)
{
    const int tid = threadIdx.x, lane = tid & 63, w = tid >> 6;
    const int wr = w >> 1, wc = w & 1;
    const int row0 = blockIdx.x * 32 + wr * 16;
    const int col0 = blockIdx.y * 32 + wc * 16;
    const int frow = lane & 15, kgrp = lane >> 4;
    f32x4 acc = {0, 0, 0, 0};
    const unsigned* ap = hpk + (row0 + frow) * 512 + kgrp * 8;
    const u16* bph = Mt_hi + (col0 + frow) * 512 + kgrp * 8;
    const u16* bpl = Mt_lo + (col0 + frow) * 512 + kgrp * 8;
    #pragma unroll 4
    for (int ks = 0; ks < 16; ++ks) {
        const u32x4 a0 = *(const u32x4*)(ap + ks * 32);
        const u32x4 a1 = *(const u32x4*)(ap + ks * 32 + 4);
        s16x8 ah, al;
        #pragma unroll
        for (int i = 0; i < 4; ++i) {
            ah[i]     = (short)(u16)a0[i];
            al[i]     = (short)(u16)(a0[i] >> 16);
            ah[4 + i] = (short)(u16)a1[i];
            al[4 + i] = (short)(u16)(a1[i] >> 16);
        }
        const s16x8 bh = *(const s16x8*)(bph + ks * 32);
        const s16x8 bl = *(const s16x8*)(bpl + ks * 32);
        acc = MFMA(ah, bh, acc);
        acc = MFMA(al, bh, acc);
        acc = MFMA(ah, bl, acc);
        acc = MFMA(al, bl, acc);
    }
    #pragma unroll
    for (int r = 0; r < 4; ++r)
        qt[(row0 + kgrp * 4 + r) * 512 + col0 + frow] = acc[r];
}

__global__ __launch_bounds__(256) void dense_out(const float* __restrict__ qt,
        const unsigned* __restrict__ hpk,
        const float* __restrict__ W1, const float* __restrict__ b1,
        const float* __restrict__ W2, const float* __restrict__ b2, float* __restrict__ out)
{
    const int r    = blockIdx.x * 4 + (threadIdx.x >> 6);
    const int lane = threadIdx.x & 63;
    int qi, ri;
    if (r < 256) { qi = r; ri = r; }
    else { const int g = (r - 256) >> 8; const int b = (r - 256) & 255; qi = b; ri = (b + g + 1) & 255; }

    float p[10];
    #pragma unroll
    for (int u = 0; u < 10; ++u) p[u] = 0.0f;
    for (int k = lane; k < 512; k += 64) {
        const float xq = qt[qi * 512 + k];
        #pragma unroll
        for (int u = 0; u < 10; ++u) p[u] += xq * W1[k * 10 + u];
    }
    for (int k = lane; k < 512; k += 64) {
        const unsigned v = hpk[(256 + ri) * 512 + k];
        const float xr = bf2f((u16)v) + bf2f((u16)(v >> 16));
        #pragma unroll
        for (int u = 0; u < 10; ++u) p[u] += xr * W1[(512 + k) * 10 + u];
    }
    #pragma unroll
    for (int off = 32; off; off >>= 1) {
        #pragma unroll
        for (int u = 0; u < 10; ++u) p[u] += __shfl_xor(p[u], off);
    }
    float s = b2[0];
    #pragma unroll
    for (int u = 0; u < 10; ++u) {
        const float h1 = fmaxf(p[u] + b1[u], 0.0f);
        s += h1 * W2[u];
    }
    if (lane == 0) out[r] = fmaxf(s, 0.0f);
}

extern "C" void kernel_launch(void* const* d_in, const int* in_sizes, int n_in,
                              void* d_out, int out_size, void* d_ws, size_t ws_size,
                              hipStream_t stream)
{
    const float* emb  = (const float*)d_in[0];
    const float* Wk   = (const float*)d_in[1];
    const float* bias = (const float*)d_in[2];
    const float* wi   = (const float*)d_in[3];
    const float* wf   = (const float*)d_in[4];
    const float* wo   = (const float*)d_in[5];
    const float* M    = (const float*)d_in[6];
    const float* W1   = (const float*)d_in[7];
    const float* b1   = (const float*)d_in[8];
    const float* W2   = (const float*)d_in[9];
    const float* b2   = (const float*)d_in[10];
    const int*   qtok = (const int*)d_in[11];
    const int*   rtok = (const int*)d_in[12];
    const int*   qlen = (const int*)d_in[13];
    const int*   rlen = (const int*)d_in[14];
    float* out = (float*)d_out;

    // workspace layout (16B-aligned)
    char* ws = (char*)d_ws;
    u16*      Wt_hi = (u16*)(ws + 0);             // 3,145,728
    u16*      Wt_lo = (u16*)(ws + 3145728);       // 3,145,728
    u16*      Mt_hi = (u16*)(ws + 6291456);       //   524,288
    u16*      Mt_lo = (u16*)(ws + 6815744);       //   524,288
    unsigned* h0p   = (unsigned*)(ws + 7340032);  // 1,048,576
    unsigned* h1p   = (unsigned*)(ws + 8388608);  // 1,048,576
    float*    qt    = (float*)(ws + 9437184);     //   524,288
    unsigned* ctr   = (unsigned*)(ws + 9961472);  //     4,096 (4 sets x 1KB)
    unsigned* h2p   = (unsigned*)(ws + 9965568);  // 1,048,576 (shadow)
    unsigned* h3p   = (unsigned*)(ws + 11014144); // 1,048,576 (shadow)
    const size_t NEED_SHADOW = 12062720ull;

    transpose_split<<<dim3(64, 24), dim3(32, 8), 0, stream>>>(Wk, Wt_hi, Wt_lo, 768, 2048);
    transpose_split<<<dim3(16, 16), dim3(32, 8), 0, stream>>>(M, Mt_hi, Mt_lo, 512, 512);
    zero_state<<<1024, 256, 0, stream>>>(h0p, ctr);

    // real kernel (bit-identical R13 path)
    lstm_persist<0><<<256, 256, 0, stream>>>(emb, qtok, rtok, qlen, rlen,
                                             Wt_hi, Wt_lo, bias, wi, wf, wo,
                                             h0p, h1p, ctr);

    // shadow ablations (scratch planes + counters; outputs never consumed)
    if (ws_size >= NEED_SHADOW) {
        lstm_persist<1><<<256, 256, 0, stream>>>(emb, qtok, rtok, qlen, rlen,
                                                 Wt_hi, Wt_lo, bias, wi, wf, wo,
                                                 h2p, h3p, ctr + 256);
        lstm_persist<2><<<256, 256, 0, stream>>>(emb, qtok, rtok, qlen, rlen,
                                                 Wt_hi, Wt_lo, bias, wi, wf, wo,
                                                 h2p, h3p, ctr + 512);
        lstm_persist<4><<<256, 256, 0, stream>>>(emb, qtok, rtok, qlen, rlen,
                                                 Wt_hi, Wt_lo, bias, wi, wf, wo,
                                                 h2p, h3p, ctr + 768);
    }

    // 128 steps (even) => final h lives in h0p
    qt_kernel<<<dim3(8, 16), 256, 0, stream>>>(h0p, Mt_hi, Mt_lo, qt);
    dense_out<<<320, 256, 0, stream>>>(qt, h0p, W1, b1, W2, b2, out);
}

// Round 16
// 2791.740 us; speedup vs baseline: 3.6407x; 3.6407x over previous
//
#include <hip/hip_runtime.h>

// DualEncoderLSTMDense: dual peephole-LSTM encoders (shared weights) + M-projection + tiny MLP.
// B=256, L=128, E=256, H=512, VOCAB=90000, NUM_NEG=4, forget_bias=2.0.
//
// Round 16: R13 base (passing, 2.97ms) + PIPELINED h loads WITHOUT inline asm.
// R14 diagnosis: 1 wave/SIMD + per-ks JIT atomic loads -> ~16 exposed ~800cy MALL
// round-trips/step = the 21us stall. Relaxed atomic loads carry no legalizer waitcnt,
// so issuing them back-to-back pipelines them. Here: per half (8 ks) issue all 32 u64
// relaxed atomic loads into a fully-unrolled register array, sched_barrier(0), then
// consume. Same addresses/values/MFMA order as R13 -> bit-identical (absmax 1.953125e-3).
// R15's inline-asm scheme (silent launch failure + rule-#18 hazard) is abandoned.

typedef unsigned short u16;
typedef unsigned long long u64;
typedef __attribute__((ext_vector_type(8))) short    s16x8;
typedef __attribute__((ext_vector_type(4))) float    f32x4;
typedef __attribute__((ext_vector_type(4))) unsigned u32x4;

#define MFMA(a, b, c) __builtin_amdgcn_mfma_f32_16x16x32_bf16((a), (b), (c), 0, 0, 0)

__device__ __forceinline__ u16 f2bf(float f) {
    union { float f; unsigned u; } v; v.f = f;
    unsigned r = v.u + 0x7FFFu + ((v.u >> 16) & 1u);
    return (u16)(r >> 16);
}
__device__ __forceinline__ float bf2f(u16 h) {
    union { unsigned u; float f; } v; v.u = ((unsigned)h) << 16;
    return v.f;
}
__device__ __forceinline__ float sigm(float x) { return 1.0f / (1.0f + expf(-x)); }

// ---- transpose fp32 [R][C] -> bf16 hi/lo planes [C][R] ----
__global__ __launch_bounds__(256) void transpose_split(const float* __restrict__ src,
        u16* __restrict__ dhi, u16* __restrict__ dlo, int R, int C)
{
    __shared__ float tile[32][33];
    const int bx = blockIdx.x * 32;
    const int by = blockIdx.y * 32;
    for (int i = threadIdx.y; i < 32; i += 8)
        tile[i][threadIdx.x] = src[(size_t)(by + i) * C + bx + threadIdx.x];
    __syncthreads();
    for (int i = threadIdx.y; i < 32; i += 8) {
        float v = tile[threadIdx.x][i];
        u16 hi = f2bf(v);
        size_t o = (size_t)(bx + i) * R + by + threadIdx.x;
        dhi[o] = hi;
        dlo[o] = f2bf(v - bf2f(hi));
    }
}

__global__ __launch_bounds__(256) void zero_state(unsigned* __restrict__ h0p,
        unsigned* __restrict__ ctr)
{
    const int i = blockIdx.x * 256 + threadIdx.x;   // grid 1024*256 = 262144
    h0p[i] = 0;
    if (i < 8) ctr[i * 32] = 0;
}

// ---- persistent LSTM: all 128 steps, both encoders (512 batch rows) ----
// 256 blocks (1/CU): rowTile = bid&7 (64 batch rows), hidTile = bid>>3 (16 hid cols).
__global__ __launch_bounds__(256, 1) void lstm_persist(
        const float* __restrict__ emb, const int* __restrict__ qtok, const int* __restrict__ rtok,
        const int* __restrict__ qlen, const int* __restrict__ rlen,
        const u16* __restrict__ Wt_hi, const u16* __restrict__ Wt_lo,   // [2048][768]
        const float* __restrict__ bias, const float* __restrict__ wi,
        const float* __restrict__ wf, const float* __restrict__ wo,
        unsigned* __restrict__ h0p, unsigned* __restrict__ h1p,         // packed h planes
        unsigned* __restrict__ ctr)
{
    __shared__ u16 whi_h[32768];   // 64 KiB: W_hi rows [4g*16c] x K 256..767, XOR-swizzled

    const int tid = threadIdx.x, lane = tid & 63, w = tid >> 6;
    const int bid = blockIdx.x;
    const int rowTile = bid & 7, hidTile = bid >> 3;
    const int row0 = rowTile * 64 + w * 16, hid0 = hidTile * 16;
    const int frow = lane & 15, kgrp = lane >> 4;
    const int sw = (frow & 7) << 4;

    // ---- stage h-part W_hi into LDS (once): 64 rows x 64 chunks of 16B ----
    for (int i = tid; i < 4096; i += 256) {
        const int gc = i >> 6, c16 = i & 63;
        const int g = gc >> 4, cc = gc & 15;
        const s16x8 v = *(const s16x8*)(Wt_hi + (size_t)(g * 512 + hid0 + cc) * 768 + 256 + c16 * 8);
        *(s16x8*)((char*)whi_h + ((gc * 1024 + c16 * 16) ^ ((gc & 7) << 4))) = v;
    }

    const int   ohid = hid0 + frow;
    const float bi  = bias[ohid];
    const float bj  = bias[512 + ohid];
    const float bff = bias[1024 + ohid];
    const float bo  = bias[1536 + ohid];
    const float wiv = wi[ohid], wfv = wf[ohid], wov = wo[ohid];
    const int   arow = row0 + frow;
    const int*  tokp = (arow < 256) ? (qtok + arow * 128) : (rtok + (arow - 256) * 128);
    const u16*  whi_base[4];
    const u16*  wlo_base[4];
    #pragma unroll
    for (int g = 0; g < 4; ++g) {
        whi_base[g] = Wt_hi + (size_t)(g * 512 + hid0 + frow) * 768;
        wlo_base[g] = Wt_lo + (size_t)(g * 512 + hid0 + frow) * 768;
    }
    int lenv[4];
    #pragma unroll
    for (int r = 0; r < 4; ++r) {
        const int rr = row0 + kgrp * 4 + r;
        lenv[r] = (rr < 256) ? qlen[rr] : rlen[rr - 256];
    }
    float c_reg[4] = {0, 0, 0, 0}, h_reg[4] = {0, 0, 0, 0};

    __syncthreads();   // LDS W staged

    unsigned* myctr = ctr + rowTile * 32;

    for (int t = 0; t < 128; ++t) {
        const unsigned* rd = (t & 1) ? h1p : h0p;
        unsigned*       wr = (t & 1) ? h0p : h1p;

        // ---- x-part (token-dependent only; overlaps barrier stragglers) ----
        const int    tok  = tokp[t];
        const float* xrow = emb + (size_t)tok * 256 + kgrp * 8;
        f32x4 fv[16];
        #pragma unroll
        for (int i = 0; i < 16; ++i)
            fv[i] = *(const f32x4*)(xrow + (i >> 1) * 32 + (i & 1) * 4);

        f32x4 acc[4] = {{0,0,0,0},{0,0,0,0},{0,0,0,0},{0,0,0,0}};

        // x-part, K 0..255: split fp32 gather into 2 planes; bh/bl streamed; 3 products
        #pragma unroll
        for (int ks = 0; ks < 8; ++ks) {
            const f32x4 v0 = fv[2 * ks], v1 = fv[2 * ks + 1];
            const float vv[8] = {v0[0], v0[1], v0[2], v0[3], v1[0], v1[1], v1[2], v1[3]};
            s16x8 xh, xl;
            #pragma unroll
            for (int e = 0; e < 8; ++e) {
                const u16 hb = f2bf(vv[e]);
                xh[e] = (short)hb;
                xl[e] = (short)f2bf(vv[e] - bf2f(hb));
            }
            const int kk = ks * 32 + kgrp * 8;
            #pragma unroll
            for (int g = 0; g < 4; ++g) {
                const s16x8 bh = *(const s16x8*)(whi_base[g] + kk);
                const s16x8 bl = *(const s16x8*)(wlo_base[g] + kk);
                acc[g] = MFMA(xh, bh, acc[g]);
                acc[g] = MFMA(xl, bh, acc[g]);
                acc[g] = MFMA(xh, bl, acc[g]);
            }
        }

        // ---- wave-autonomous wait: 128 publishes (32 blocks x 4 waves) per step ----
        if (lane == 0) {
            const unsigned target = 128u * (unsigned)t;
            while (__hip_atomic_load(myctr, __ATOMIC_RELAXED, __HIP_MEMORY_SCOPE_AGENT) < target)
                __builtin_amdgcn_s_sleep(2);
        }
        asm volatile("" ::: "memory");

        const unsigned* hrd = rd + arow * 512 + kgrp * 8;

        // ---- h-part, K 256..767, in 2 halves of 8 ks ----
        // Per half: issue ALL 32 u64 relaxed atomic loads back-to-back (no legalizer
        // waitcnt between relaxed atomics -> they pipeline; waitcnt pass inserts counted
        // vmcnt before each use), fence the scheduler, then consume. Values and MFMA
        // order identical to R13 -> bit-identical output.
        #pragma unroll
        for (int half = 0; half < 2; ++half) {
            u64 hv[32];
            #pragma unroll
            for (int i = 0; i < 32; ++i) {
                const int ks = half * 8 + (i >> 2);
                hv[i] = __hip_atomic_load((const u64*)(hrd + ks * 32 + (i & 3) * 2),
                                          __ATOMIC_RELAXED, __HIP_MEMORY_SCOPE_AGENT);
            }
            __builtin_amdgcn_sched_barrier(0);   // keep loads batched ahead of consumption
            #pragma unroll
            for (int j = 0; j < 8; ++j) {
                const int ks = half * 8 + j;
                const int kh = ks * 32;
                s16x8 ah, al;
                #pragma unroll
                for (int i = 0; i < 4; ++i) {
                    const u64 v = hv[j * 4 + i];
                    const unsigned w0 = (unsigned)v, w1 = (unsigned)(v >> 32);
                    ah[2 * i]     = (short)(u16)w0;
                    al[2 * i]     = (short)(u16)(w0 >> 16);
                    ah[2 * i + 1] = (short)(u16)w1;
                    al[2 * i + 1] = (short)(u16)(w1 >> 16);
                }
                #pragma unroll
                for (int g = 0; g < 4; ++g) {
                    const int gr = g * 16 + frow;
                    const s16x8 bh = *(const s16x8*)((const char*)whi_h + ((gr * 1024 + (kh + kgrp * 8) * 2) ^ sw));
                    const s16x8 bl = *(const s16x8*)(wlo_base[g] + 256 + kh + kgrp * 8);
                    acc[g] = MFMA(ah, bh, acc[g]);
                    acc[g] = MFMA(al, bh, acc[g]);
                    acc[g] = MFMA(ah, bl, acc[g]);
                    acc[g] = MFMA(al, bl, acc[g]);
                }
            }
        }

        // ---- gates + peepholes + masking; publish h packed via sc1 atomic store ----
        #pragma unroll
        for (int r = 0; r < 4; ++r) {
            const float cold = c_reg[r];
            const float ig = sigm(acc[0][r] + bi + wiv * cold);
            const float jg = tanhf(acc[1][r] + bj);
            const float fg = sigm(acc[2][r] + bff + wfv * cold + 2.0f);
            const float cn = fg * cold + ig * jg;
            const float og = sigm(acc[3][r] + bo + wov * cn);
            const float hn = og * tanhf(cn);
            const bool upd = (t < lenv[r]);
            c_reg[r] = upd ? cn : c_reg[r];
            h_reg[r] = upd ? hn : h_reg[r];
            const int off = (row0 + kgrp * 4 + r) * 512 + ohid;
            const u16 hb = f2bf(h_reg[r]);
            const u16 lb = f2bf(h_reg[r] - bf2f(hb));
            __hip_atomic_store(wr + off, ((unsigned)lb << 16) | (unsigned)hb,
                               __ATOMIC_RELAXED, __HIP_MEMORY_SCOPE_AGENT);
        }

        // ---- per-wave publish: drain this wave's stores, one relaxed add ----
        asm volatile("s_waitcnt vmcnt(0)" ::: "memory");
        if (lane == 0)
            __hip_atomic_fetch_add(myctr, 1u, __ATOMIC_RELAXED, __HIP_MEMORY_SCOPE_AGENT);
        asm volatile("" ::: "memory");
    }
}

// ---- qt[256][512] = q_h @ M (MFMA, h from packed plane, M hi+lo, 4 products) ----
__global__ __launch_bounds__(256) void qt_kernel(
        const unsigned* __restrict__ hpk,
        const u16* __restrict__ Mt_hi, const u16* __restrict__ Mt_lo, float* __restrict__ qt)
{
    const int tid = threadIdx.x, lane = tid & 63, w = tid >> 6;
    const int wr = w >> 1, wc = w & 1;
    const int row0 = blockIdx.x * 32 + wr * 16;
    const int col0 = blockIdx.y * 32 + wc * 16;
    const int frow = lane & 15, kgrp = lane >> 4;
    f32x4 acc = {0, 0, 0, 0};
    const unsigned* ap = hpk + (row0 + frow) * 512 + kgrp * 8;
    const u16* bph = Mt_hi + (col0 + frow) * 512 + kgrp * 8;
    const u16* bpl = Mt_lo + (col0 + frow) * 512 + kgrp * 8;
    #pragma unroll 4
    for (int ks = 0; ks < 16; ++ks) {
        const u32x4 a0 = *(const u32x4*)(ap + ks * 32);
        const u32x4 a1 = *(const u32x4*)(ap + ks * 32 + 4);
        s16x8 ah, al;
        #pragma unroll
        for (int i = 0; i < 4; ++i) {
            ah[i]     = (short)(u16)a0[i];
            al[i]     = (short)(u16)(a0[i] >> 16);
            ah[4 + i] = (short)(u16)a1[i];
            al[4 + i] = (short)(u16)(a1[i] >> 16);
        }
        const s16x8 bh = *(const s16x8*)(bph + ks * 32);
        const s16x8 bl = *(const s16x8*)(bpl + ks * 32);
        acc = MFMA(ah, bh, acc);
        acc = MFMA(al, bh, acc);
        acc = MFMA(ah, bl, acc);
        acc = MFMA(al, bl, acc);
    }
    #pragma unroll
    for (int r = 0; r < 4; ++r)
        qt[(row0 + kgrp * 4 + r) * 512 + col0 + frow] = acc[r];
}

// ---- final MLP: 1280 rows, one wave per row ----
__global__ __launch_bounds__(256) void dense_out(const float* __restrict__ qt,
        const unsigned* __restrict__ hpk,
        const float* __restrict__ W1, const float* __restrict__ b1,
        const float* __restrict__ W2, const float* __restrict__ b2, float* __restrict__ out)
{
    const int r    = blockIdx.x * 4 + (threadIdx.x >> 6);
    const int lane = threadIdx.x & 63;
    int qi, ri;
    if (r < 256) { qi = r; ri = r; }
    else { const int g = (r - 256) >> 8; const int b = (r - 256) & 255; qi = b; ri = (b + g + 1) & 255; }

    float p[10];
    #pragma unroll
    for (int u = 0; u < 10; ++u) p[u] = 0.0f;
    for (int k = lane; k < 512; k += 64) {
        const float xq = qt[qi * 512 + k];
        #pragma unroll
        for (int u = 0; u < 10; ++u) p[u] += xq * W1[k * 10 + u];
    }
    for (int k = lane; k < 512; k += 64) {
        const unsigned v = hpk[(256 + ri) * 512 + k];
        const float xr = bf2f((u16)v) + bf2f((u16)(v >> 16));
        #pragma unroll
        for (int u = 0; u < 10; ++u) p[u] += xr * W1[(512 + k) * 10 + u];
    }
    #pragma unroll
    for (int off = 32; off; off >>= 1) {
        #pragma unroll
        for (int u = 0; u < 10; ++u) p[u] += __shfl_xor(p[u], off);
    }
    float s = b2[0];
    #pragma unroll
    for (int u = 0; u < 10; ++u) {
        const float h1 = fmaxf(p[u] + b1[u], 0.0f);
        s += h1 * W2[u];
    }
    if (lane == 0) out[r] = fmaxf(s, 0.0f);
}

extern "C" void kernel_launch(void* const* d_in, const int* in_sizes, int n_in,
                              void* d_out, int out_size, void* d_ws, size_t ws_size,
                              hipStream_t stream)
{
    const float* emb  = (const float*)d_in[0];
    const float* Wk   = (const float*)d_in[1];
    const float* bias = (const float*)d_in[2];
    const float* wi   = (const float*)d_in[3];
    const float* wf   = (const float*)d_in[4];
    const float* wo   = (const float*)d_in[5];
    const float* M    = (const float*)d_in[6];
    const float* W1   = (const float*)d_in[7];
    const float* b1   = (const float*)d_in[8];
    const float* W2   = (const float*)d_in[9];
    const float* b2   = (const float*)d_in[10];
    const int*   qtok = (const int*)d_in[11];
    const int*   rtok = (const int*)d_in[12];
    const int*   qlen = (const int*)d_in[13];
    const int*   rlen = (const int*)d_in[14];
    float* out = (float*)d_out;

    // workspace layout (16B-aligned); total ~10.5 MB
    char* ws = (char*)d_ws;
    u16*      Wt_hi = (u16*)(ws + 0);            // 3,145,728
    u16*      Wt_lo = (u16*)(ws + 3145728);      // 3,145,728
    u16*      Mt_hi = (u16*)(ws + 6291456);      //   524,288
    u16*      Mt_lo = (u16*)(ws + 6815744);      //   524,288
    unsigned* h0p   = (unsigned*)(ws + 7340032); // 1,048,576 (packed lo|hi)
    unsigned* h1p   = (unsigned*)(ws + 8388608); // 1,048,576
    float*    qt    = (float*)(ws + 9437184);    //   524,288
    unsigned* ctr   = (unsigned*)(ws + 9961472); // 8 counters @ 128B stride

    transpose_split<<<dim3(64, 24), dim3(32, 8), 0, stream>>>(Wk, Wt_hi, Wt_lo, 768, 2048);
    transpose_split<<<dim3(16, 16), dim3(32, 8), 0, stream>>>(M, Mt_hi, Mt_lo, 512, 512);
    zero_state<<<1024, 256, 0, stream>>>(h0p, ctr);

    lstm_persist<<<256, 256, 0, stream>>>(emb, qtok, rtok, qlen, rlen,
                                          Wt_hi, Wt_lo, bias, wi, wf, wo,
                                          h0p, h1p, ctr);

    // 128 steps (even) => final h lives in h0p
    qt_kernel<<<dim3(8, 16), 256, 0, stream>>>(h0p, Mt_hi, Mt_lo, qt);
    dense_out<<<320, 256, 0, stream>>>(qt, h0p, W1, b1, W2, b2, out);
}